// Round 1
// baseline (792.995 us; speedup 1.0000x reference)
//
#include <hip/hip_runtime.h>

#define NN 100000
#define NE 1600000
#define DD 128
#define NG 128
#define NC 10
#define SCAN_ELEMS 1024
#define NSCAN ((NN + SCAN_ELEMS - 1) / SCAN_ELEMS)  // 98

// ---------------- degree / dinv ----------------
__global__ __launch_bounds__(256) void deg_k(const int* __restrict__ col, int* __restrict__ degi) {
    int e = blockIdx.x * 256 + threadIdx.x;
    if (e < NE) atomicAdd(&degi[col[e]], 1);
}

__global__ __launch_bounds__(256) void dinv_k(const int* __restrict__ degi, float* __restrict__ dinv) {
    int i = blockIdx.x * 256 + threadIdx.x;
    if (i < NN) dinv[i] = rsqrtf((float)degi[i] + 1.0f);  // +1 self-loop
}

// ---------------- exclusive scan of degi -> offsets ----------------
__global__ __launch_bounds__(256) void scan1_k(const int* __restrict__ degi, int* __restrict__ offs,
                                               int* __restrict__ partials) {
    __shared__ int tmp[256];
    int tid = threadIdx.x;
    int base = blockIdx.x * SCAN_ELEMS + tid * 4;
    int v[4];
    int s = 0;
#pragma unroll
    for (int j = 0; j < 4; ++j) {
        int idx = base + j;
        v[j] = (idx < NN) ? degi[idx] : 0;
        s += v[j];
    }
    tmp[tid] = s;
    __syncthreads();
    for (int off = 1; off < 256; off <<= 1) {
        int t = (tid >= off) ? tmp[tid - off] : 0;
        __syncthreads();
        tmp[tid] += t;
        __syncthreads();
    }
    int excl = tmp[tid] - s;
    int run = excl;
#pragma unroll
    for (int j = 0; j < 4; ++j) {
        int idx = base + j;
        if (idx < NN) offs[idx] = run;
        run += v[j];
    }
    if (tid == 255) partials[blockIdx.x] = tmp[255];
}

__global__ __launch_bounds__(128) void scan2_k(const int* __restrict__ partials, int* __restrict__ psc) {
    __shared__ int tmp[128];
    int tid = threadIdx.x;
    int v = (tid < NSCAN) ? partials[tid] : 0;
    tmp[tid] = v;
    __syncthreads();
    for (int off = 1; off < 128; off <<= 1) {
        int t = (tid >= off) ? tmp[tid - off] : 0;
        __syncthreads();
        tmp[tid] += t;
        __syncthreads();
    }
    int excl = tmp[tid] - v;
    if (tid < NSCAN) psc[tid] = excl;
    if (tid == 127) psc[NSCAN] = tmp[127];  // total (== NE)
}

__global__ __launch_bounds__(256) void scan3_k(int* __restrict__ offs, int* __restrict__ cursor,
                                               const int* __restrict__ psc) {
    int i = blockIdx.x * 256 + threadIdx.x;
    if (i < NN) {
        int v = offs[i] + psc[i >> 10];
        offs[i] = v;
        cursor[i] = v;
        if (i == 0) offs[NN] = psc[NSCAN];
    }
}

// ---------------- CSR fill ----------------
__global__ __launch_bounds__(256) void fill_k(const int* __restrict__ row, const int* __restrict__ col,
                                              int* __restrict__ cursor, int* __restrict__ csr_src) {
    int e = blockIdx.x * 256 + threadIdx.x;
    if (e < NE) {
        int c = col[e];
        int pos = atomicAdd(&cursor[c], 1);
        csr_src[pos] = row[e];
    }
}

// ---------------- GEMM: out[r][:] = dinv[r] * (X[r][:] @ W)  (128x128 W) ----------------
// 32 rows / block, 256 threads, each thread 4 rows x 4 cols.
__global__ __launch_bounds__(256) void gemm_scaled_k(const float* __restrict__ X,
                                                     const float* __restrict__ W,
                                                     const float* __restrict__ dinv,
                                                     float* __restrict__ out) {
    __shared__ float xs[32 * 130];
    int tid = threadIdx.x;
    long base = (long)blockIdx.x * 32 * DD;
#pragma unroll
    for (int i = 0; i < 16; ++i) {
        int idx = tid + i * 256;
        int r = idx >> 7, k = idx & 127;
        xs[r * 130 + k] = X[base + idx];
    }
    __syncthreads();
    int cg = tid & 31;   // cols 4cg..4cg+3
    int rg = tid >> 5;   // rows 4rg..4rg+3
    const float4* W4 = (const float4*)W;
    float4 a0 = {0, 0, 0, 0}, a1 = {0, 0, 0, 0}, a2 = {0, 0, 0, 0}, a3 = {0, 0, 0, 0};
    const float* x0p = xs + (4 * rg + 0) * 130;
    const float* x1p = xs + (4 * rg + 1) * 130;
    const float* x2p = xs + (4 * rg + 2) * 130;
    const float* x3p = xs + (4 * rg + 3) * 130;
#pragma unroll 8
    for (int k = 0; k < DD; ++k) {
        float4 w = W4[k * 32 + cg];
        float x0 = x0p[k], x1 = x1p[k], x2 = x2p[k], x3 = x3p[k];
        a0.x = fmaf(x0, w.x, a0.x); a0.y = fmaf(x0, w.y, a0.y);
        a0.z = fmaf(x0, w.z, a0.z); a0.w = fmaf(x0, w.w, a0.w);
        a1.x = fmaf(x1, w.x, a1.x); a1.y = fmaf(x1, w.y, a1.y);
        a1.z = fmaf(x1, w.z, a1.z); a1.w = fmaf(x1, w.w, a1.w);
        a2.x = fmaf(x2, w.x, a2.x); a2.y = fmaf(x2, w.y, a2.y);
        a2.z = fmaf(x2, w.z, a2.z); a2.w = fmaf(x2, w.w, a2.w);
        a3.x = fmaf(x3, w.x, a3.x); a3.y = fmaf(x3, w.y, a3.y);
        a3.z = fmaf(x3, w.z, a3.z); a3.w = fmaf(x3, w.w, a3.w);
    }
    int row = blockIdx.x * 32 + 4 * rg;
    float d;
    float4* o;
    d = dinv[row + 0]; o = (float4*)(out + (long)(row + 0) * DD);
    o[cg] = make_float4(d * a0.x, d * a0.y, d * a0.z, d * a0.w);
    d = dinv[row + 1]; o = (float4*)(out + (long)(row + 1) * DD);
    o[cg] = make_float4(d * a1.x, d * a1.y, d * a1.z, d * a1.w);
    d = dinv[row + 2]; o = (float4*)(out + (long)(row + 2) * DD);
    o[cg] = make_float4(d * a2.x, d * a2.y, d * a2.z, d * a2.w);
    d = dinv[row + 3]; o = (float4*)(out + (long)(row + 3) * DD);
    o[cg] = make_float4(d * a3.x, d * a3.y, d * a3.z, d * a3.w);
}

// ---------------- aggregation: out[i] = relu(dinv[i]*(sum_{src in CSR[i]} h[src] + h[i]) + b) ----------------
// one wave (64 lanes) per node, float2 per lane (128 dims)
__global__ __launch_bounds__(256) void agg_k(const float* __restrict__ hp, const float* __restrict__ dinv,
                                             const int* __restrict__ offs, const int* __restrict__ csr_src,
                                             const float* __restrict__ bias, float* __restrict__ out) {
    int node = (blockIdx.x << 2) + (threadIdx.x >> 6);
    if (node >= NN) return;
    int lane = threadIdx.x & 63;
    const float2* hp2 = (const float2*)hp;
    int s = offs[node];
    int e_end = offs[node + 1];
    float2 acc = hp2[(long)node * 64 + lane];  // self-loop contribution
    int e = s;
    for (; e + 2 <= e_end; e += 2) {
        int s0 = csr_src[e];
        int s1 = csr_src[e + 1];
        float2 v0 = hp2[(long)s0 * 64 + lane];
        float2 v1 = hp2[(long)s1 * 64 + lane];
        acc.x += v0.x + v1.x;
        acc.y += v0.y + v1.y;
    }
    if (e < e_end) {
        int s0 = csr_src[e];
        float2 v0 = hp2[(long)s0 * 64 + lane];
        acc.x += v0.x;
        acc.y += v0.y;
    }
    float dv = dinv[node];
    float2 b = ((const float2*)bias)[lane];
    float2 o;
    o.x = fmaxf(fmaf(dv, acc.x, b.x), 0.0f);
    o.y = fmaxf(fmaf(dv, acc.y, b.y), 0.0f);
    ((float2*)out)[(long)node * 64 + lane] = o;
}

// ---------------- pooling ----------------
__global__ __launch_bounds__(256) void starts_k(const int* __restrict__ batch, int* __restrict__ starts) {
    int g = threadIdx.x;
    if (g > NG) return;
    if (g == NG) {
        starts[NG] = NN;
        return;
    }
    int lo = 0, hi = NN;
    while (lo < hi) {
        int mid = (lo + hi) >> 1;
        if (batch[mid] < g) lo = mid + 1;
        else hi = mid;
    }
    starts[g] = lo;
}

__global__ __launch_bounds__(128) void pool_k(const float* __restrict__ h, const int* __restrict__ starts,
                                              float* __restrict__ gsum, int* __restrict__ gcnt) {
    int g = blockIdx.x;
    int t = threadIdx.x;
    int s = starts[g], e = starts[g + 1];
    float acc = 0.0f;
    for (int r = s; r < e; ++r) acc += h[(long)r * DD + t];
    gsum[g * DD + t] = acc;
    if (t == 0) gcnt[g] = e - s;
}

__global__ __launch_bounds__(256) void final_k(const float* __restrict__ gsum, const int* __restrict__ gcnt,
                                               const float* __restrict__ Wlin, const float* __restrict__ blin,
                                               float* __restrict__ out) {
    int idx = blockIdx.x * 256 + threadIdx.x;
    if (idx >= NG * NC) return;
    int g = idx / NC, c = idx % NC;
    float inv = 1.0f / fmaxf((float)gcnt[g], 1.0f);
    float acc = blin[c];
    for (int k = 0; k < DD; ++k) acc = fmaf(gsum[g * DD + k] * inv, Wlin[k * NC + c], acc);
    out[idx] = acc;
}

extern "C" void kernel_launch(void* const* d_in, const int* in_sizes, int n_in,
                              void* d_out, int out_size, void* d_ws, size_t ws_size,
                              hipStream_t stream) {
    const float* x    = (const float*)d_in[0];
    const int*   ei   = (const int*)d_in[1];    // [2][NE]: row=src, col=dst
    const int*   batch = (const int*)d_in[2];
    const float* W1   = (const float*)d_in[3];
    const float* b1   = (const float*)d_in[4];
    const float* W2   = (const float*)d_in[5];
    const float* b2   = (const float*)d_in[6];
    const float* Wlin = (const float*)d_in[7];
    const float* blin = (const float*)d_in[8];
    float* out = (float*)d_out;

    const int* erow = ei;
    const int* ecol = ei + NE;

    char* ws = (char*)d_ws;
    size_t off = 0;
    auto alloc = [&](size_t bytes) {
        void* p = ws + off;
        off = (off + bytes + 255) & ~(size_t)255;
        return p;
    };
    float* bufA   = (float*)alloc((size_t)NN * DD * 4);  // h' (scaled transform)
    float* bufB   = (float*)alloc((size_t)NN * DD * 4);  // layer output
    float* dinv   = (float*)alloc(NN * 4);
    int*   degi   = (int*)alloc(NN * 4);
    int*   offs   = (int*)alloc((NN + 1) * 4);
    int*   cursor = (int*)alloc(NN * 4);
    int*   csrsrc = (int*)alloc((size_t)NE * 4);
    int*   partials = (int*)alloc(NSCAN * 4);
    int*   psc    = (int*)alloc((NSCAN + 1) * 4);
    float* gsum   = (float*)alloc(NG * DD * 4);
    int*   gcnt   = (int*)alloc(NG * 4);
    int*   starts = (int*)alloc((NG + 1) * 4);
    (void)ws_size;

    hipMemsetAsync(degi, 0, NN * 4, stream);

    deg_k<<<(NE + 255) / 256, 256, 0, stream>>>(ecol, degi);
    dinv_k<<<(NN + 255) / 256, 256, 0, stream>>>(degi, dinv);
    scan1_k<<<NSCAN, 256, 0, stream>>>(degi, offs, partials);
    scan2_k<<<1, 128, 0, stream>>>(partials, psc);
    scan3_k<<<(NN + 255) / 256, 256, 0, stream>>>(offs, cursor, psc);
    fill_k<<<(NE + 255) / 256, 256, 0, stream>>>(erow, ecol, cursor, csrsrc);

    // layer 1: x -> bufA (scaled transform) -> bufB (aggregated + relu)
    gemm_scaled_k<<<NN / 32, 256, 0, stream>>>(x, W1, dinv, bufA);
    agg_k<<<(NN + 3) / 4, 256, 0, stream>>>(bufA, dinv, offs, csrsrc, b1, bufB);
    // layer 2: bufB -> bufA -> bufB
    gemm_scaled_k<<<NN / 32, 256, 0, stream>>>(bufB, W2, dinv, bufA);
    agg_k<<<(NN + 3) / 4, 256, 0, stream>>>(bufA, dinv, offs, csrsrc, b2, bufB);

    // pooling + head
    starts_k<<<1, 256, 0, stream>>>(batch, starts);
    pool_k<<<NG, 128, 0, stream>>>(bufB, starts, gsum, gcnt);
    final_k<<<(NG * NC + 255) / 256, 256, 0, stream>>>(gsum, gcnt, Wlin, blin, out);
}

// Round 2
// 614.714 us; speedup vs baseline: 1.2900x; 1.2900x over previous
//
#include <hip/hip_runtime.h>

#define NN 100000
#define NE 1600000
#define DD 128
#define NG 128
#define NC 10
#define SCAN_ELEMS 1024
#define NSCAN ((NN + SCAN_ELEMS - 1) / SCAN_ELEMS)  // 98
#define POOL_WAVES 2048

// ---------------- degree / dinv ----------------
__global__ __launch_bounds__(256) void deg_k(const int* __restrict__ col, int* __restrict__ degi) {
    int e = blockIdx.x * 256 + threadIdx.x;
    if (e < NE) atomicAdd(&degi[col[e]], 1);
}

__global__ __launch_bounds__(256) void dinv_k(const int* __restrict__ degi, float* __restrict__ dinv) {
    int i = blockIdx.x * 256 + threadIdx.x;
    if (i < NN) dinv[i] = rsqrtf((float)degi[i] + 1.0f);  // +1 self-loop
}

// ---------------- exclusive scan of degi -> offsets ----------------
__global__ __launch_bounds__(256) void scan1_k(const int* __restrict__ degi, int* __restrict__ offs,
                                               int* __restrict__ partials) {
    __shared__ int tmp[256];
    int tid = threadIdx.x;
    int base = blockIdx.x * SCAN_ELEMS + tid * 4;
    int v[4];
    int s = 0;
#pragma unroll
    for (int j = 0; j < 4; ++j) {
        int idx = base + j;
        v[j] = (idx < NN) ? degi[idx] : 0;
        s += v[j];
    }
    tmp[tid] = s;
    __syncthreads();
    for (int off = 1; off < 256; off <<= 1) {
        int t = (tid >= off) ? tmp[tid - off] : 0;
        __syncthreads();
        tmp[tid] += t;
        __syncthreads();
    }
    int excl = tmp[tid] - s;
    int run = excl;
#pragma unroll
    for (int j = 0; j < 4; ++j) {
        int idx = base + j;
        if (idx < NN) offs[idx] = run;
        run += v[j];
    }
    if (tid == 255) partials[blockIdx.x] = tmp[255];
}

__global__ __launch_bounds__(128) void scan2_k(const int* __restrict__ partials, int* __restrict__ psc) {
    __shared__ int tmp[128];
    int tid = threadIdx.x;
    int v = (tid < NSCAN) ? partials[tid] : 0;
    tmp[tid] = v;
    __syncthreads();
    for (int off = 1; off < 128; off <<= 1) {
        int t = (tid >= off) ? tmp[tid - off] : 0;
        __syncthreads();
        tmp[tid] += t;
        __syncthreads();
    }
    int excl = tmp[tid] - v;
    if (tid < NSCAN) psc[tid] = excl;
    if (tid == 127) psc[NSCAN] = tmp[127];  // total (== NE)
}

__global__ __launch_bounds__(256) void scan3_k(int* __restrict__ offs, int* __restrict__ cursor,
                                               const int* __restrict__ psc) {
    int i = blockIdx.x * 256 + threadIdx.x;
    if (i < NN) {
        int v = offs[i] + psc[i >> 10];
        offs[i] = v;
        cursor[i] = v;
        if (i == 0) offs[NN] = psc[NSCAN];
    }
}

// ---------------- CSR fill ----------------
__global__ __launch_bounds__(256) void fill_k(const int* __restrict__ row, const int* __restrict__ col,
                                              int* __restrict__ cursor, int* __restrict__ csr_src) {
    int e = blockIdx.x * 256 + threadIdx.x;
    if (e < NE) {
        int c = col[e];
        int pos = atomicAdd(&cursor[c], 1);
        csr_src[pos] = row[e];
    }
}

// ---------------- GEMM: out[r][:] = dinv[r] * (X[r][:] @ W)  (128x128 W) ----------------
__global__ __launch_bounds__(256) void gemm_scaled_k(const float* __restrict__ X,
                                                     const float* __restrict__ W,
                                                     const float* __restrict__ dinv,
                                                     float* __restrict__ out) {
    __shared__ float xs[32 * 130];
    int tid = threadIdx.x;
    long base = (long)blockIdx.x * 32 * DD;
#pragma unroll
    for (int i = 0; i < 16; ++i) {
        int idx = tid + i * 256;
        int r = idx >> 7, k = idx & 127;
        xs[r * 130 + k] = X[base + idx];
    }
    __syncthreads();
    int cg = tid & 31;   // cols 4cg..4cg+3
    int rg = tid >> 5;   // rows 4rg..4rg+3
    const float4* W4 = (const float4*)W;
    float4 a0 = {0, 0, 0, 0}, a1 = {0, 0, 0, 0}, a2 = {0, 0, 0, 0}, a3 = {0, 0, 0, 0};
    const float* x0p = xs + (4 * rg + 0) * 130;
    const float* x1p = xs + (4 * rg + 1) * 130;
    const float* x2p = xs + (4 * rg + 2) * 130;
    const float* x3p = xs + (4 * rg + 3) * 130;
#pragma unroll 8
    for (int k = 0; k < DD; ++k) {
        float4 w = W4[k * 32 + cg];
        float x0 = x0p[k], x1 = x1p[k], x2 = x2p[k], x3 = x3p[k];
        a0.x = fmaf(x0, w.x, a0.x); a0.y = fmaf(x0, w.y, a0.y);
        a0.z = fmaf(x0, w.z, a0.z); a0.w = fmaf(x0, w.w, a0.w);
        a1.x = fmaf(x1, w.x, a1.x); a1.y = fmaf(x1, w.y, a1.y);
        a1.z = fmaf(x1, w.z, a1.z); a1.w = fmaf(x1, w.w, a1.w);
        a2.x = fmaf(x2, w.x, a2.x); a2.y = fmaf(x2, w.y, a2.y);
        a2.z = fmaf(x2, w.z, a2.z); a2.w = fmaf(x2, w.w, a2.w);
        a3.x = fmaf(x3, w.x, a3.x); a3.y = fmaf(x3, w.y, a3.y);
        a3.z = fmaf(x3, w.z, a3.z); a3.w = fmaf(x3, w.w, a3.w);
    }
    int row = blockIdx.x * 32 + 4 * rg;
    float d;
    float4* o;
    d = dinv[row + 0]; o = (float4*)(out + (long)(row + 0) * DD);
    o[cg] = make_float4(d * a0.x, d * a0.y, d * a0.z, d * a0.w);
    d = dinv[row + 1]; o = (float4*)(out + (long)(row + 1) * DD);
    o[cg] = make_float4(d * a1.x, d * a1.y, d * a1.z, d * a1.w);
    d = dinv[row + 2]; o = (float4*)(out + (long)(row + 2) * DD);
    o[cg] = make_float4(d * a2.x, d * a2.y, d * a2.z, d * a2.w);
    d = dinv[row + 3]; o = (float4*)(out + (long)(row + 3) * DD);
    o[cg] = make_float4(d * a3.x, d * a3.y, d * a3.z, d * a3.w);
}

// ---------------- aggregation: out[i] = relu(dinv[i]*(sum_{src in CSR[i]} h[src] + h[i]) + b) ----------------
__global__ __launch_bounds__(256) void agg_k(const float* __restrict__ hp, const float* __restrict__ dinv,
                                             const int* __restrict__ offs, const int* __restrict__ csr_src,
                                             const float* __restrict__ bias, float* __restrict__ out) {
    int node = (blockIdx.x << 2) + (threadIdx.x >> 6);
    if (node >= NN) return;
    int lane = threadIdx.x & 63;
    const float2* hp2 = (const float2*)hp;
    int s = offs[node];
    int e_end = offs[node + 1];
    float2 acc = hp2[(long)node * 64 + lane];  // self-loop contribution
    int e = s;
    for (; e + 2 <= e_end; e += 2) {
        int s0 = csr_src[e];
        int s1 = csr_src[e + 1];
        float2 v0 = hp2[(long)s0 * 64 + lane];
        float2 v1 = hp2[(long)s1 * 64 + lane];
        acc.x += v0.x + v1.x;
        acc.y += v0.y + v1.y;
    }
    if (e < e_end) {
        int s0 = csr_src[e];
        float2 v0 = hp2[(long)s0 * 64 + lane];
        acc.x += v0.x;
        acc.y += v0.y;
    }
    float dv = dinv[node];
    float2 b = ((const float2*)bias)[lane];
    float2 o;
    o.x = fmaxf(fmaf(dv, acc.x, b.x), 0.0f);
    o.y = fmaxf(fmaf(dv, acc.y, b.y), 0.0f);
    ((float2*)out)[(long)node * 64 + lane] = o;
}

// ---------------- pooling: 2048 waves, each owns a contiguous node range; ----------------
// batch is sorted, so accumulate per-wave and flush on graph-boundary via atomicAdd.
__global__ __launch_bounds__(256) void pool2_k(const float* __restrict__ h, const int* __restrict__ batch,
                                               float* __restrict__ gsum) {
    int wave = (blockIdx.x * 256 + threadIdx.x) >> 6;
    int lane = threadIdx.x & 63;
    const int per = (NN + POOL_WAVES - 1) / POOL_WAVES;  // 49
    int s = wave * per;
    int e = min(s + per, NN);
    if (s >= e) return;
    const float2* h2 = (const float2*)h;
    float2 acc = {0.0f, 0.0f};
    int cur = batch[s];
    for (int r = s; r < e; ++r) {
        int b = batch[r];
        if (b != cur) {
            atomicAdd(&gsum[cur * DD + 2 * lane], acc.x);
            atomicAdd(&gsum[cur * DD + 2 * lane + 1], acc.y);
            acc.x = 0.0f; acc.y = 0.0f;
            cur = b;
        }
        float2 v = h2[(long)r * 64 + lane];
        acc.x += v.x;
        acc.y += v.y;
    }
    atomicAdd(&gsum[cur * DD + 2 * lane], acc.x);
    atomicAdd(&gsum[cur * DD + 2 * lane + 1], acc.y);
}

// ---------------- starts (graph boundaries via binary search; batch sorted) ----------------
__global__ __launch_bounds__(256) void starts_k(const int* __restrict__ batch, int* __restrict__ starts) {
    int g = threadIdx.x;
    if (g > NG) return;
    if (g == NG) {
        starts[NG] = NN;
        return;
    }
    int lo = 0, hi = NN;
    while (lo < hi) {
        int mid = (lo + hi) >> 1;
        if (batch[mid] < g) lo = mid + 1;
        else hi = mid;
    }
    starts[g] = lo;
}

__global__ __launch_bounds__(256) void final_k(const float* __restrict__ gsum, const int* __restrict__ starts,
                                               const float* __restrict__ Wlin, const float* __restrict__ blin,
                                               float* __restrict__ out) {
    int idx = blockIdx.x * 256 + threadIdx.x;
    if (idx >= NG * NC) return;
    int g = idx / NC, c = idx % NC;
    int cnt = starts[g + 1] - starts[g];
    float inv = 1.0f / fmaxf((float)cnt, 1.0f);
    float acc = blin[c];
    for (int k = 0; k < DD; ++k) acc = fmaf(gsum[g * DD + k] * inv, Wlin[k * NC + c], acc);
    out[idx] = acc;
}

extern "C" void kernel_launch(void* const* d_in, const int* in_sizes, int n_in,
                              void* d_out, int out_size, void* d_ws, size_t ws_size,
                              hipStream_t stream) {
    const float* x    = (const float*)d_in[0];
    const int*   ei   = (const int*)d_in[1];    // [2][NE]: row=src, col=dst
    const int*   batch = (const int*)d_in[2];
    const float* W1   = (const float*)d_in[3];
    const float* b1   = (const float*)d_in[4];
    const float* W2   = (const float*)d_in[5];
    const float* b2   = (const float*)d_in[6];
    const float* Wlin = (const float*)d_in[7];
    const float* blin = (const float*)d_in[8];
    float* out = (float*)d_out;

    const int* erow = ei;
    const int* ecol = ei + NE;

    char* ws = (char*)d_ws;
    size_t off = 0;
    auto alloc = [&](size_t bytes) {
        void* p = ws + off;
        off = (off + bytes + 255) & ~(size_t)255;
        return p;
    };
    float* bufA   = (float*)alloc((size_t)NN * DD * 4);  // h' (scaled transform)
    float* bufB   = (float*)alloc((size_t)NN * DD * 4);  // layer output
    float* dinv   = (float*)alloc(NN * 4);
    int*   degi   = (int*)alloc(NN * 4);
    int*   offs   = (int*)alloc((NN + 1) * 4);
    int*   cursor = (int*)alloc(NN * 4);
    int*   csrsrc = (int*)alloc((size_t)NE * 4);
    int*   partials = (int*)alloc(NSCAN * 4);
    int*   psc    = (int*)alloc((NSCAN + 1) * 4);
    float* gsum   = (float*)alloc(NG * DD * 4);
    int*   starts = (int*)alloc((NG + 1) * 4);
    (void)ws_size;

    hipMemsetAsync(degi, 0, NN * 4, stream);
    hipMemsetAsync(gsum, 0, NG * DD * 4, stream);

    deg_k<<<(NE + 255) / 256, 256, 0, stream>>>(ecol, degi);
    dinv_k<<<(NN + 255) / 256, 256, 0, stream>>>(degi, dinv);
    scan1_k<<<NSCAN, 256, 0, stream>>>(degi, offs, partials);
    scan2_k<<<1, 128, 0, stream>>>(partials, psc);
    scan3_k<<<(NN + 255) / 256, 256, 0, stream>>>(offs, cursor, psc);
    fill_k<<<(NE + 255) / 256, 256, 0, stream>>>(erow, ecol, cursor, csrsrc);

    // layer 1: x -> bufA (scaled transform) -> bufB (aggregated + relu)
    gemm_scaled_k<<<NN / 32, 256, 0, stream>>>(x, W1, dinv, bufA);
    agg_k<<<(NN + 3) / 4, 256, 0, stream>>>(bufA, dinv, offs, csrsrc, b1, bufB);
    // layer 2: bufB -> bufA -> bufB
    gemm_scaled_k<<<NN / 32, 256, 0, stream>>>(bufB, W2, dinv, bufA);
    agg_k<<<(NN + 3) / 4, 256, 0, stream>>>(bufA, dinv, offs, csrsrc, b2, bufB);

    // pooling + head
    starts_k<<<1, 256, 0, stream>>>(batch, starts);
    pool2_k<<<POOL_WAVES / 4, 256, 0, stream>>>(bufB, batch, gsum);
    final_k<<<(NG * NC + 255) / 256, 256, 0, stream>>>(gsum, starts, Wlin, blin, out);
}